// Round 1
// 572.513 us; speedup vs baseline: 1.2795x; 1.2795x over previous
//
#include <hip/hip_runtime.h>
#include <math.h>

// LSTM autoencoder, MFMA, fp16 single-product numerics.
// R10 = R9 structure spread over all 256 CUs: BT 16->8, NBLK 128->256.
// Rationale (rocprof): 128 blocks left half the GPU idle; active CUs were
// ~84% issue-busy with VALU:MFMA = 4:1, i.e. per-CU cell-VALU issue was the
// wall-time limiter. Halving rows/block halves per-CU cell work; MFMA M=16
// tiles run half-empty (MFMA pipe had 5x headroom). Cell work is rebalanced
// across all 64 lanes via __shfl_xor(.,32): the MFMA acc layout puts valid
// rows 0-7 in lanes 0-31 only, so lanes 32-63 take over rows {2,3,6,7} and
// every lane computes 2 cells (a masked q<2 guard would save no issue slots).
// Dead plane rows 8-15 are kept exactly zero (NaN-free half-empty MFMAs);
// per-row numerics identical to R9.
//  - NO BN fold (R5/R7 showed fold+requantization costs 2x accuracy).
//  - B fragments pinned in AGPRs; encoder/decoder sets disjoint.
// 256 blocks x 512 threads, BT=8 rows/block.

typedef _Float16 half8 __attribute__((ext_vector_type(8)));
typedef __attribute__((ext_vector_type(4))) float floatx4;

#define TT 128
#define NF 8
#define BT 8
#define NBLK 256
#define NTH 512

// packed-fragment start indices (in 512-ushort frag units, single fp16 plane)
#define FS_Z1 0     // K'=160 (Wr1 128 | Wk1 8 | pad), N=512 : 32 tiles x 5 ks
#define FS_Z2 160   // K'=192 (Wk2 128 | Wr2 64),     N=256 : 16 x 6
#define FS_X3 256   // K =64  (Wk3),                  N=256 : 16 x 2
#define FS_Z3 288   // K =64  (Wr3),                  N=256 : 16 x 2
#define FS_Z4 320   // K'=192 (Wk4 64 | Wr4 128),     N=512 : 32 x 6
#define FS_DN 512   // K =128 (Wd), N=16 (cols 8-15 zero) : 1 x 4
#define N_FRAGS 516

#define MFMAH(a,b,c) __builtin_amdgcn_mfma_f32_16x16x32_f16((a),(b),(c),0,0,0)
#define PINA(v) asm volatile("" : "+a"(v))

__device__ __forceinline__ float sigmoid_(float x){ return 1.0f/(1.0f+__expf(-x)); }
__device__ __forceinline__ float selu_(float x){
    const float alpha = 1.6732632423543772f, scale = 1.0507009873554805f;
    return x > 0.0f ? scale*x : scale*alpha*(__expf(x)-1.0f);
}

// ---------------- pack kernel: RAW weights -> B-fragment order, fp16 --------
__global__ void pack_kernel(const float* __restrict__ Wk1, const float* __restrict__ Wr1,
                            const float* __restrict__ Wk2, const float* __restrict__ Wr2,
                            const float* __restrict__ Wk3, const float* __restrict__ Wr3,
                            const float* __restrict__ Wk4, const float* __restrict__ Wr4,
                            const float* __restrict__ Wd, unsigned short* __restrict__ ws)
{
    const int g = blockIdx.x;
    const int l = threadIdx.x;
    int blob, fs, KS;
    if      (g < FS_Z2){ blob = 0; fs = FS_Z1; KS = 5; }
    else if (g < FS_X3){ blob = 1; fs = FS_Z2; KS = 6; }
    else if (g < FS_Z3){ blob = 2; fs = FS_X3; KS = 2; }
    else if (g < FS_Z4){ blob = 3; fs = FS_Z3; KS = 2; }
    else if (g < FS_DN){ blob = 4; fs = FS_Z4; KS = 6; }
    else               { blob = 5; fs = FS_DN; KS = 4; }
    const int fl = g - fs;
    const int tile = fl / KS, kk = fl % KS;
    const int col = tile * 16 + (l & 15);
    const int k0  = kk * 32 + (l >> 4) * 8;

    half8 v8;
    #pragma unroll
    for (int j = 0; j < 8; ++j){
        const int k = k0 + j;
        float v = 0.0f;
        switch (blob){
            case 0: v = (k < 128) ? Wr1[k*512 + col] : (k < 136 ? Wk1[(k-128)*512 + col] : 0.0f); break;
            case 1: v = (k < 128) ? Wk2[k*256 + col] : Wr2[(k-128)*256 + col]; break;
            case 2: v = Wk3[k*256 + col]; break;
            case 3: v = Wr3[k*256 + col]; break;
            case 4: v = (k < 64) ? Wk4[k*512 + col] : Wr4[(k-64)*512 + col]; break;
            case 5: v = (col < 8) ? Wd[k*8 + col] : 0.0f; break;
        }
        v8[j] = (_Float16)v;    // RNE
    }
    *(half8*)(ws + (size_t)g*512 + l*8) = v8;
}

// ---------------- main kernel ------------------------------------------------
__global__ __launch_bounds__(NTH, 1) void lstm_ae_mfma(
    const float* __restrict__ x,
    const float* __restrict__ b1, const float* __restrict__ b2,
    const float* __restrict__ b3, const float* __restrict__ b4,
    const float* __restrict__ bd,
    const float* __restrict__ g1, const float* __restrict__ be1, const float* __restrict__ m1, const float* __restrict__ v1,
    const float* __restrict__ g2, const float* __restrict__ be2, const float* __restrict__ m2, const float* __restrict__ v2,
    const float* __restrict__ g3, const float* __restrict__ be3, const float* __restrict__ m3, const float* __restrict__ v3,
    const float* __restrict__ g4, const float* __restrict__ be4, const float* __restrict__ m4, const float* __restrict__ v4,
    const unsigned short* __restrict__ WS,
    float* __restrict__ out)
{
    // A-fragment planes, single fp16: [kk][lane*8 + j]; rows 8-15 stay zero
    __shared__ __align__(16) _Float16 AZ1[2][5][512];   // h1 (kk 0-3) + x (kk 4)
    __shared__ __align__(16) _Float16 AH1B[4][512];     // BN1(h1)
    __shared__ __align__(16) _Float16 AH2[2][2][512];
    __shared__ __align__(16) _Float16 AH3[2][2][512];
    __shared__ __align__(16) _Float16 AH3B[2][512];     // enc planes, then BN3(h3)
    __shared__ __align__(16) _Float16 AH4[2][4][512];
    __shared__ __align__(16) _Float16 AH4B[4][512];     // BN4(h4)
    __shared__ __align__(16) float ZSC[16*260];         // encoder z2 scratch

    const int tid = threadIdx.x;
    const int w = tid >> 6, l = tid & 63;
    const int l15 = l & 15, q = l >> 4;
    const bool hi = (l >= 32);
    // lane's 2 owned rows after shfl rebalance: q=0->{0,1} q=1->{4,5} q=2->{2,3} q=3->{6,7}
    const int rowA = 4*(q&1) + 2*(q>>1);
    const int b0 = blockIdx.x * BT;

    // ---- per-lane constants ----
    const int u1 = 16*w + l15;                   // z1/z4 cell column (0..127)
    const int kk1 = u1 >> 5;
    const int sbase1 = ((u1>>3)&3)*128 + (u1&7);
    const float s1v = g1[u1]*rsqrtf(v1[u1]+1e-3f), t1v = be1[u1]-m1[u1]*s1v;
    const float s4v = g4[u1]*rsqrtf(v4[u1]+1e-3f), t4v = be4[u1]-m4[u1]*s4v;

    // encoder cell2 mapping: ONE cell/thread (512 threads = 8 rows x 64 units)
    const int c2row = tid & 7;
    const int u2 = tid >> 3;                     // 0..63
    const int kk2 = u2 >> 5;
    const int s2idx = ((u2>>3)&3)*128 + c2row*8 + (u2&7);
    const float s2v = g2[u2]*rsqrtf(v2[u2]+1e-3f), t2v = be2[u2]-m2[u2]*s2v;

    // decoder cell3 mapping (waves 0-3 own all gates of column u3)
    const int u3 = 16*(w&3) + l15;               // 0..63
    const int kk3 = u3 >> 5;
    const int sbase3 = ((u3>>3)&3)*128 + (u3&7);
    const float s3v = g3[u3]*rsqrtf(v3[u3]+1e-3f);
    const float t3v = be3[u3]-m3[u3]*s3v;

    float z1b[4], z4b[4], z2b[2];
    #pragma unroll
    for (int i = 0; i < 4; ++i){
        z1b[i] = b1[(w + 8*i)*16 + l15];
        z4b[i] = b4[(w + 8*i)*16 + l15];
    }
    #pragma unroll
    for (int i = 0; i < 2; ++i)
        z2b[i] = b2[32*w + 16*i + l15];
    float b3v[4];
    #pragma unroll
    for (int i = 0; i < 4; ++i)
        b3v[i] = (w < 4) ? b3[((w&3) + 4*i)*16 + l15] : 0.0f;
    const float bdv = (w == 4 && l15 < 8) ? bd[l15] : 0.0f;

    // ---- encoder weights pinned in AGPRs ----
    half8 wz1[4][5], wz2[2][6];
    #pragma unroll
    for (int i = 0; i < 4; ++i)
        #pragma unroll
        for (int kk = 0; kk < 5; ++kk){
            wz1[i][kk] = *(const half8*)(WS + (size_t)(FS_Z1 + (w+8*i)*5 + kk)*512 + l*8);
            PINA(wz1[i][kk]);
        }
    #pragma unroll
    for (int i = 0; i < 2; ++i)
        #pragma unroll
        for (int kk = 0; kk < 6; ++kk){
            wz2[i][kk] = *(const half8*)(WS + (size_t)(FS_Z2 + (2*w+i)*6 + kk)*512 + l*8);
            PINA(wz2[i][kk]);
        }

    // ---- prologue: zero ALL state planes (rows 8-15 must be exact zeros
    //      forever so half-empty M=16 MFMAs stay clean), stage x[0] ----
    for (int i = tid; i < 2560; i += NTH) ((int*)AZ1)[i] = 0;
    for (int i = tid; i < 1024; i += NTH){
        ((int*)AH1B)[i] = 0; ((int*)AH2)[i] = 0; ((int*)AH3)[i] = 0; ((int*)AH4B)[i] = 0;
    }
    for (int i = tid; i < 2048; i += NTH) ((int*)AH4)[i] = 0;
    for (int i = tid; i < 512;  i += NTH) ((int*)AH3B)[i] = 0;
    if (tid < 64){
        int row = tid >> 3, j = tid & 7;
        AZ1[0][4][row*8+j] = (_Float16)x[(size_t)(b0+row)*(TT*NF) + j];
    }
    float c1r[2] = {0,0}, c4r[2] = {0,0};
    float c3r[2] = {0,0};
    float c2r = 0.0f;
    __syncthreads();

    // ===================== encoder (2 barriers/step) =====================
    int p = 0;
    for (int t = 0; t < TT; ++t){
        float xnext = 0.0f;
        if (tid < 64 && t+1 < TT)
            xnext = x[(size_t)(b0+(tid>>3))*(TT*NF) + (size_t)(t+1)*NF + (tid&7)];

        // --- z1: A fp16 from LDS, B fp16 from AGPR (1 MFMA per tile-kk) ---
        floatx4 acc[4];
        #pragma unroll
        for (int i = 0; i < 4; ++i) acc[i] = (floatx4){z1b[i],z1b[i],z1b[i],z1b[i]};
        #pragma unroll
        for (int kk = 0; kk < 5; ++kk){
            half8 a = *(const half8*)&AZ1[p][kk][l*8];
            #pragma unroll
            for (int i = 0; i < 4; ++i)
                acc[i] = MFMAH(a, wz1[i][kk], acc[i]);
        }
        // --- rebalance: lanes 32-63 take rows {2,3,6,7} from lanes 0-31 ---
        float ga[2][4];
        #pragma unroll
        for (int i = 0; i < 4; ++i){
            float t2 = __shfl_xor(acc[i][2], 32);
            float t3 = __shfl_xor(acc[i][3], 32);
            ga[0][i] = hi ? t2 : acc[i][0];
            ga[1][i] = hi ? t3 : acc[i][1];
        }
        // --- cell1 (2 cells/lane): raw h (AZ1) + BN1(h) (AH1B) ---
        #pragma unroll
        for (int r = 0; r < 2; ++r){
            float ig = sigmoid_(ga[r][0]);
            float fg = sigmoid_(ga[r][1]);
            float gg = selu_(ga[r][2]);
            float og = sigmoid_(ga[r][3]);
            float c = fg*c1r[r] + ig*gg; c1r[r] = c;
            float h = og*selu_(c);
            const int s = sbase1 + (rowA+r)*8;
            AZ1[p^1][kk1][s] = (_Float16)h;
            AH1B[kk1][s]     = (_Float16)(h*s1v + t1v);
        }
        if (tid < 64 && t+1 < TT){
            int row = tid >> 3, j = tid & 7;
            AZ1[p^1][4][row*8+j] = (_Float16)xnext;
        }
        __syncthreads();

        // --- z2 -> ZSC (A: BN1 planes kk<4, recurrent h2 kk>=4) ---
        floatx4 a2[2];
        #pragma unroll
        for (int i = 0; i < 2; ++i) a2[i] = (floatx4){z2b[i],z2b[i],z2b[i],z2b[i]};
        #pragma unroll
        for (int kk = 0; kk < 6; ++kk){
            half8 a = (kk < 4) ? *(const half8*)&AH1B[kk][l*8]
                               : *(const half8*)&AH2[p][kk-4][l*8];
            #pragma unroll
            for (int i = 0; i < 2; ++i)
                a2[i] = MFMAH(a, wz2[i][kk], a2[i]);
        }
        #pragma unroll
        for (int i = 0; i < 2; ++i)
            #pragma unroll
            for (int r = 0; r < 4; ++r)
                ZSC[(q*4+r)*260 + 32*w + 16*i + l15] = a2[i][r];
        __syncthreads();

        // --- cell2 (1 cell/thread, rows 0-7 only) ---
        {
            const float* zr = &ZSC[c2row*260];
            float ig = sigmoid_(zr[u2]);
            float fg = sigmoid_(zr[64+u2]);
            float gg = selu_(zr[128+u2]);
            float og = sigmoid_(zr[192+u2]);
            float c = fg*c2r + ig*gg; c2r = c;
            float h = og*selu_(c);
            AH2[p^1][kk2][s2idx] = (_Float16)h;
        }
        p ^= 1;
    }
    __syncthreads();

    // ===================== bottleneck =====================
    // encb = BN2(h2_final) -> AH3B planes (rows 8-15 remain zero)
    {
        float h2v = (float)AH2[p][kk2][s2idx];
        AH3B[kk2][s2idx] = (_Float16)(h2v*s2v + t2v);
    }
    __syncthreads();
    // xz3 = b3 + encb@Wk3  (one-time)
    floatx4 xz3r[4];
    if (w < 4){
        #pragma unroll
        for (int i = 0; i < 4; ++i) xz3r[i] = (floatx4){b3v[i],b3v[i],b3v[i],b3v[i]};
        #pragma unroll
        for (int kk = 0; kk < 2; ++kk){
            half8 a = *(const half8*)&AH3B[kk][l*8];
            #pragma unroll
            for (int i = 0; i < 4; ++i){
                half8 b = *(const half8*)(WS + (size_t)(FS_X3 + ((w&3)+4*i)*2 + kk)*512 + l*8);
                xz3r[i] = MFMAH(a, b, xz3r[i]);
            }
        }
    }

    // ---- decoder weights pinned in AGPRs (encoder AGPRs now dead) ----
    half8 wz4[4][6], wrole[8];
    #pragma unroll
    for (int i = 0; i < 4; ++i)
        #pragma unroll
        for (int kk = 0; kk < 6; ++kk){
            wz4[i][kk] = *(const half8*)(WS + (size_t)(FS_Z4 + (w+8*i)*6 + kk)*512 + l*8);
            PINA(wz4[i][kk]);
        }
    if (w < 4){
        #pragma unroll
        for (int i = 0; i < 4; ++i)
            #pragma unroll
            for (int kk = 0; kk < 2; ++kk){
                wrole[i*2+kk] = *(const half8*)(WS + (size_t)(FS_Z3 + ((w&3)+4*i)*2 + kk)*512 + l*8);
                PINA(wrole[i*2+kk]);
            }
    } else if (w == 4){
        #pragma unroll
        for (int kk = 0; kk < 4; ++kk){
            wrole[kk] = *(const half8*)(WS + (size_t)(FS_DN + kk)*512 + l*8);
            PINA(wrole[kk]);
        }
    }
    __syncthreads();   // AH3B reuse: enc-plane reads must finish before cell3 writes

    // ===================== decoder (2 barriers/step) =====================
    p = 0;
    for (int t = 0; t < TT; ++t){
        if (w < 4){
            // --- z3 (waves0-3, all 4 gates) + cell3 in registers ---
            floatx4 a3[4];
            #pragma unroll
            for (int i = 0; i < 4; ++i) a3[i] = xz3r[i];
            #pragma unroll
            for (int kk = 0; kk < 2; ++kk){
                half8 a = *(const half8*)&AH3[p][kk][l*8];
                #pragma unroll
                for (int i = 0; i < 4; ++i)
                    a3[i] = MFMAH(a, wrole[i*2+kk], a3[i]);
            }
            float ga[2][4];
            #pragma unroll
            for (int i = 0; i < 4; ++i){
                float t2 = __shfl_xor(a3[i][2], 32);
                float t3 = __shfl_xor(a3[i][3], 32);
                ga[0][i] = hi ? t2 : a3[i][0];
                ga[1][i] = hi ? t3 : a3[i][1];
            }
            #pragma unroll
            for (int r = 0; r < 2; ++r){
                float ig = sigmoid_(ga[r][0]);
                float fg = sigmoid_(ga[r][1]);
                float gg = selu_(ga[r][2]);
                float og = sigmoid_(ga[r][3]);
                float c = fg*c3r[r] + ig*gg; c3r[r] = c;
                float h = og*selu_(c);
                const int s = sbase3 + (rowA+r)*8;
                AH3[p^1][kk3][s] = (_Float16)h;
                AH3B[kk3][s]     = (_Float16)(h*s3v + t3v);
            }
        } else if (w == 4 && t > 0){
            // --- dense(t-1) on wave4 (A = BN4 planes, B = Wd) ---
            floatx4 ad = (floatx4){bdv,bdv,bdv,bdv};
            #pragma unroll
            for (int kk = 0; kk < 4; ++kk){
                half8 a = *(const half8*)&AH4B[kk][l*8];
                ad = MFMAH(a, wrole[kk], ad);
            }
            if (!hi && l15 < 8){
                #pragma unroll
                for (int r = 0; r < 4; ++r)
                    out[(size_t)(b0 + q*4 + r)*(TT*NF) + (size_t)(t-1)*NF + l15] = ad[r];
            }
        }
        __syncthreads();

        // --- z4 + cell4 (all waves); A kk<2 = BN3 planes, kk>=2 = raw h4 ---
        floatx4 a4[4];
        #pragma unroll
        for (int i = 0; i < 4; ++i) a4[i] = (floatx4){z4b[i],z4b[i],z4b[i],z4b[i]};
        #pragma unroll
        for (int kk = 0; kk < 6; ++kk){
            half8 a = (kk < 2) ? *(const half8*)&AH3B[kk][l*8]
                               : *(const half8*)&AH4[p][kk-2][l*8];
            #pragma unroll
            for (int i = 0; i < 4; ++i)
                a4[i] = MFMAH(a, wz4[i][kk], a4[i]);
        }
        float ga[2][4];
        #pragma unroll
        for (int i = 0; i < 4; ++i){
            float t2 = __shfl_xor(a4[i][2], 32);
            float t3 = __shfl_xor(a4[i][3], 32);
            ga[0][i] = hi ? t2 : a4[i][0];
            ga[1][i] = hi ? t3 : a4[i][1];
        }
        #pragma unroll
        for (int r = 0; r < 2; ++r){
            float ig = sigmoid_(ga[r][0]);
            float fg = sigmoid_(ga[r][1]);
            float gg = selu_(ga[r][2]);
            float og = sigmoid_(ga[r][3]);
            float c = fg*c4r[r] + ig*gg; c4r[r] = c;
            float h = og*selu_(c);
            const int s = sbase1 + (rowA+r)*8;
            AH4[p^1][kk1][s] = (_Float16)h;
            AH4B[kk1][s]     = (_Float16)(h*s4v + t4v);
        }
        __syncthreads();
        p ^= 1;
    }

    // epilogue: dense for t = TT-1 (wave4)
    if (w == 4){
        floatx4 ad = (floatx4){bdv,bdv,bdv,bdv};
        #pragma unroll
        for (int kk = 0; kk < 4; ++kk){
            half8 a = *(const half8*)&AH4B[kk][l*8];
            ad = MFMAH(a, wrole[kk], ad);
        }
        if (!hi && l15 < 8){
            #pragma unroll
            for (int r = 0; r < 4; ++r)
                out[(size_t)(b0 + q*4 + r)*(TT*NF) + (size_t)(TT-1)*NF + l15] = ad[r];
        }
    }
}

extern "C" void kernel_launch(void* const* d_in, const int* in_sizes, int n_in,
                              void* d_out, int out_size, void* d_ws, size_t ws_size,
                              hipStream_t stream) {
    const float* x   = (const float*)d_in[0];
    const float* Wk1 = (const float*)d_in[1];  const float* Wr1 = (const float*)d_in[2];
    const float* b1  = (const float*)d_in[3];
    const float* g1  = (const float*)d_in[4];  const float* be1 = (const float*)d_in[5];
    const float* m1  = (const float*)d_in[6];  const float* v1  = (const float*)d_in[7];
    const float* Wk2 = (const float*)d_in[8];  const float* Wr2 = (const float*)d_in[9];
    const float* b2  = (const float*)d_in[10];
    const float* g2  = (const float*)d_in[11]; const float* be2 = (const float*)d_in[12];
    const float* m2  = (const float*)d_in[13]; const float* v2  = (const float*)d_in[14];
    const float* Wk3 = (const float*)d_in[15]; const float* Wr3 = (const float*)d_in[16];
    const float* b3  = (const float*)d_in[17];
    const float* g3  = (const float*)d_in[18]; const float* be3 = (const float*)d_in[19];
    const float* m3  = (const float*)d_in[20]; const float* v3  = (const float*)d_in[21];
    const float* Wk4 = (const float*)d_in[22]; const float* Wr4 = (const float*)d_in[23];
    const float* b4  = (const float*)d_in[24];
    const float* g4  = (const float*)d_in[25]; const float* be4 = (const float*)d_in[26];
    const float* m4  = (const float*)d_in[27]; const float* v4  = (const float*)d_in[28];
    const float* Wd  = (const float*)d_in[29]; const float* bd  = (const float*)d_in[30];

    unsigned short* ws = (unsigned short*)d_ws;

    pack_kernel<<<dim3(N_FRAGS), dim3(64), 0, stream>>>(Wk1, Wr1, Wk2, Wr2, Wk3, Wr3,
                                                        Wk4, Wr4, Wd, ws);
    lstm_ae_mfma<<<dim3(NBLK), dim3(NTH), 0, stream>>>(
        x, b1, b2, b3, b4, bd,
        g1, be1, m1, v1, g2, be2, m2, v2,
        g3, be3, m3, v3, g4, be4, m4, v4,
        (const unsigned short*)ws, (float*)d_out);
}

// Round 3
// 474.443 us; speedup vs baseline: 1.5439x; 1.2067x over previous
//
#include <hip/hip_runtime.h>
#include <math.h>

// LSTM autoencoder, MFMA, fp16 single-product numerics.
// R12 = R11 structure with the permlane asm reverted to proven shfl_xor+select
// (R11 FAILED 0.66 absmax; v_permlane32_swap_b32 inline asm was the only
// unproven primitive -- suspected swap-direction inversion. Everything else
// re-derived clean and is kept):
//  - ONE barrier per recurrent step (was 2): retimed regions
//    {z1(t+1),cell1(t+1),z2(t),cell2(t)} with double-buffered BN planes.
//  - z2 columns permuted in pack so each wave owns all 4 gates of its units:
//    cell2 is in-register (shfl_xor(32)+select then shfl_xor(8) exchange),
//    ZSC LDS round-trip and its barrier gone.
//  - sigmoid uses v_rcp_f32 (rcpf) instead of IEEE div chain (~1ulp, safe).
//  - register-neutral: 128 VGPR + 128 AGPR = 256-reg 2-wave/SIMD cliff.
//  - NO BN fold (R5/R7: fold+requantization costs 2x accuracy).
// 256 blocks x 512 threads, BT=8 rows/block.

typedef _Float16 half8 __attribute__((ext_vector_type(8)));
typedef __attribute__((ext_vector_type(4))) float floatx4;

#define TT 128
#define NF 8
#define BT 8
#define NBLK 256
#define NTH 512

// packed-fragment start indices (in 512-ushort frag units, single fp16 plane)
#define FS_Z1 0     // K'=160 (Wr1 128 | Wk1 8 | pad), N=512 : 32 tiles x 5 ks
#define FS_Z2 160   // K'=192 (Wk2 128 | Wr2 64),     N=256 : 16 x 6  (cols gate-permuted)
#define FS_X3 256   // K =64  (Wk3),                  N=256 : 16 x 2
#define FS_Z3 288   // K =64  (Wr3),                  N=256 : 16 x 2
#define FS_Z4 320   // K'=192 (Wk4 64 | Wr4 128),     N=512 : 32 x 6
#define FS_DN 512   // K =128 (Wd), N=16 (cols 8-15 zero) : 1 x 4
#define N_FRAGS 516

#define MFMAH(a,b,c) __builtin_amdgcn_mfma_f32_16x16x32_f16((a),(b),(c),0,0,0)
#define PINA(v) asm volatile("" : "+a"(v))

__device__ __forceinline__ float sigmoid_(float x){
    return __builtin_amdgcn_rcpf(1.0f + __expf(-x));
}
__device__ __forceinline__ float selu_(float x){
    const float alpha = 1.6732632423543772f, scale = 1.0507009873554805f;
    return x > 0.0f ? scale*x : scale*alpha*(__expf(x)-1.0f);
}

// ---------------- pack kernel: RAW weights -> B-fragment order, fp16 --------
__global__ void pack_kernel(const float* __restrict__ Wk1, const float* __restrict__ Wr1,
                            const float* __restrict__ Wk2, const float* __restrict__ Wr2,
                            const float* __restrict__ Wk3, const float* __restrict__ Wr3,
                            const float* __restrict__ Wk4, const float* __restrict__ Wr4,
                            const float* __restrict__ Wd, unsigned short* __restrict__ ws)
{
    const int g = blockIdx.x;
    const int l = threadIdx.x;
    int blob, fs, KS;
    if      (g < FS_Z2){ blob = 0; fs = FS_Z1; KS = 5; }
    else if (g < FS_X3){ blob = 1; fs = FS_Z2; KS = 6; }
    else if (g < FS_Z3){ blob = 2; fs = FS_X3; KS = 2; }
    else if (g < FS_Z4){ blob = 3; fs = FS_Z3; KS = 2; }
    else if (g < FS_DN){ blob = 4; fs = FS_Z4; KS = 6; }
    else               { blob = 5; fs = FS_DN; KS = 4; }
    const int fl = g - fs;
    const int tile = fl / KS, kk = fl % KS;
    const int c   = l & 15;
    const int col = tile * 16 + c;
    const int k0  = kk * 32 + (l >> 4) * 8;
    // z2 gate-permuted column: wave w=tile>>1 owns units 8w..8w+7, all 4 gates
    const int oc2 = (2*(tile&1) + (c>>3))*64 + 8*(tile>>1) + (c&7);

    half8 v8;
    #pragma unroll
    for (int j = 0; j < 8; ++j){
        const int k = k0 + j;
        float v = 0.0f;
        switch (blob){
            case 0: v = (k < 128) ? Wr1[k*512 + col] : (k < 136 ? Wk1[(k-128)*512 + col] : 0.0f); break;
            case 1: v = (k < 128) ? Wk2[k*256 + oc2] : Wr2[(k-128)*256 + oc2]; break;
            case 2: v = Wk3[k*256 + col]; break;
            case 3: v = Wr3[k*256 + col]; break;
            case 4: v = (k < 64) ? Wk4[k*512 + col] : Wr4[(k-64)*512 + col]; break;
            case 5: v = (col < 8) ? Wd[k*8 + col] : 0.0f; break;
        }
        v8[j] = (_Float16)v;    // RNE
    }
    *(half8*)(ws + (size_t)g*512 + l*8) = v8;
}

// ---------------- main kernel ------------------------------------------------
__global__ __launch_bounds__(NTH, 1) void lstm_ae_mfma(
    const float* __restrict__ x,
    const float* __restrict__ b1, const float* __restrict__ b2,
    const float* __restrict__ b3, const float* __restrict__ b4,
    const float* __restrict__ bd,
    const float* __restrict__ g1, const float* __restrict__ be1, const float* __restrict__ m1, const float* __restrict__ v1,
    const float* __restrict__ g2, const float* __restrict__ be2, const float* __restrict__ m2, const float* __restrict__ v2,
    const float* __restrict__ g3, const float* __restrict__ be3, const float* __restrict__ m3, const float* __restrict__ v3,
    const float* __restrict__ g4, const float* __restrict__ be4, const float* __restrict__ m4, const float* __restrict__ v4,
    const unsigned short* __restrict__ WS,
    float* __restrict__ out)
{
    // A-fragment planes, fp16: [buf][kk][lane*8+j]
    __shared__ __align__(16) _Float16 AZ1[2][5][512];   // h1 (kk 0-3) + x (kk 4)
    __shared__ __align__(16) _Float16 AH1B[2][4][512];  // BN1(h1), double-buffered
    __shared__ __align__(16) _Float16 AH2[2][2][512];
    __shared__ __align__(16) _Float16 AH3[2][2][512];
    __shared__ __align__(16) _Float16 AH3B[2][2][512];  // BN3(h3) dbuf; [1] = enc scratch
    __shared__ __align__(16) _Float16 AH4[2][4][512];
    __shared__ __align__(16) _Float16 AH4B[2][4][512];  // BN4(h4), double-buffered

    const int tid = threadIdx.x;
    const int w = tid >> 6, l = tid & 63;
    const int l15 = l & 15, q = l >> 4;
    const bool hi = (l >= 32);
    // lane's 2 rows after rebalance: q=0->{0,1} q=1->{4,5} q=2->{2,3} q=3->{6,7}
    const int rowA = 4*(q&1) + 2*(q>>1);
    const bool h8 = (l15 & 8) != 0;     // gate-exchange side for cell2
    const int b0 = blockIdx.x * BT;

    // ---- per-lane constants ----
    const int u1 = 16*w + l15;                   // z1/z4 cell column (0..127)
    const int kk1 = u1 >> 5;
    const int sbase1 = ((u1>>3)&3)*128 + (u1&7);
    const float s1v = g1[u1]*rsqrtf(v1[u1]+1e-3f), t1v = be1[u1]-m1[u1]*s1v;
    const float s4v = g4[u1]*rsqrtf(v4[u1]+1e-3f), t4v = be4[u1]-m4[u1]*s4v;

    // encoder cell2 mapping (gate-permuted z2): one cell/lane
    const int u2n = 8*w + (l15 & 7);             // unit 0..63
    const int row2 = rowA + (h8 ? 1 : 0);        // batch row 0..7
    const int s2w = (w&3)*128 + row2*8 + (l15&7);// index within AH2[buf][w>>2]
    const float s2v = g2[u2n]*rsqrtf(v2[u2n]+1e-3f), t2v = be2[u2n]-m2[u2n]*s2v;

    // decoder cell3 mapping (waves 0-3 own all gates of column u3)
    const int u3 = 16*(w&3) + l15;               // 0..63
    const int kk3 = u3 >> 5;
    const int sbase3 = ((u3>>3)&3)*128 + (u3&7);
    const float s3v = g3[u3]*rsqrtf(v3[u3]+1e-3f);
    const float t3v = be3[u3]-m3[u3]*s3v;

    float z1b[4], z4b[4], z2b[2];
    #pragma unroll
    for (int i = 0; i < 4; ++i){
        z1b[i] = b1[(w + 8*i)*16 + l15];
        z4b[i] = b4[(w + 8*i)*16 + l15];
    }
    #pragma unroll
    for (int i = 0; i < 2; ++i)
        z2b[i] = b2[(2*i + (l15>>3))*64 + u2n];  // permuted-column bias
    float b3v[4];
    #pragma unroll
    for (int i = 0; i < 4; ++i)
        b3v[i] = (w < 4) ? b3[((w&3) + 4*i)*16 + l15] : 0.0f;
    const float bdv = (w == 4 && l15 < 8) ? bd[l15] : 0.0f;

    // ---- encoder weights pinned in AGPRs ----
    half8 wz1[4][5], wz2[2][6];
    #pragma unroll
    for (int i = 0; i < 4; ++i)
        #pragma unroll
        for (int kk = 0; kk < 5; ++kk){
            wz1[i][kk] = *(const half8*)(WS + (size_t)(FS_Z1 + (w+8*i)*5 + kk)*512 + l*8);
            PINA(wz1[i][kk]);
        }
    #pragma unroll
    for (int i = 0; i < 2; ++i)
        #pragma unroll
        for (int kk = 0; kk < 6; ++kk){
            wz2[i][kk] = *(const half8*)(WS + (size_t)(FS_Z2 + (2*w+i)*6 + kk)*512 + l*8);
            PINA(wz2[i][kk]);
        }

    // ---- prologue: zero all planes, stage x(0) ----
    for (int i = tid; i < 2560; i += NTH) ((int*)AZ1)[i] = 0;
    for (int i = tid; i < 2048; i += NTH){
        ((int*)AH1B)[i] = 0; ((int*)AH4)[i] = 0; ((int*)AH4B)[i] = 0;
    }
    for (int i = tid; i < 1024; i += NTH){
        ((int*)AH2)[i] = 0; ((int*)AH3)[i] = 0; ((int*)AH3B)[i] = 0;
    }
    if (tid < 64)
        AZ1[0][4][(tid>>3)*8 + (tid&7)] = (_Float16)x[(size_t)(b0+(tid>>3))*(TT*NF) + (tid&7)];
    float c1r[2] = {0,0}, c4r[2] = {0,0}, c3r[2] = {0,0};
    float c2r = 0.0f, h2last = 0.0f;
    __syncthreads();

    // ===================== encoder: ONE barrier per step =====================
    // region_t: z1(t+1)+cell1(t+1) | z2(t)+cell2(t)   (t = -1 .. TT-1)
    for (int t = -1; t < TT; ++t){
        const int pe = t & 1;      // (-1)&1 == 1
        if (t + 1 < TT){
            float xnext = 0.0f;
            if (tid < 64 && t + 2 < TT)
                xnext = x[(size_t)(b0+(tid>>3))*(TT*NF) + (size_t)(t+2)*NF + (tid&7)];

            // --- z1(t+1): A from AZ1[pe^1], B from AGPR ---
            floatx4 acc[4];
            #pragma unroll
            for (int i = 0; i < 4; ++i) acc[i] = (floatx4){z1b[i],z1b[i],z1b[i],z1b[i]};
            #pragma unroll
            for (int kk = 0; kk < 5; ++kk){
                half8 a = *(const half8*)&AZ1[pe^1][kk][l*8];
                #pragma unroll
                for (int i = 0; i < 4; ++i)
                    acc[i] = MFMAH(a, wz1[i][kk], acc[i]);
            }
            // rebalance rows {2,3,6,7} to hi lanes (proven shfl_xor+select)
            float ga[2][4];
            #pragma unroll
            for (int i = 0; i < 4; ++i){
                float t2 = __shfl_xor(acc[i][2], 32);
                float t3 = __shfl_xor(acc[i][3], 32);
                ga[0][i] = hi ? t2 : acc[i][0];
                ga[1][i] = hi ? t3 : acc[i][1];
            }
            // --- cell1(t+1): raw h -> AZ1[pe], BN1 -> AH1B[pe^1] ---
            #pragma unroll
            for (int r = 0; r < 2; ++r){
                float ig = sigmoid_(ga[r][0]);
                float fg = sigmoid_(ga[r][1]);
                float gg = selu_(ga[r][2]);
                float og = sigmoid_(ga[r][3]);
                float c = fg*c1r[r] + ig*gg; c1r[r] = c;
                float h = og*selu_(c);
                const int s = sbase1 + (rowA+r)*8;
                AZ1[pe][kk1][s]    = (_Float16)h;
                AH1B[pe^1][kk1][s] = (_Float16)(h*s1v + t1v);
            }
            if (tid < 64 && t + 2 < TT)
                AZ1[pe][4][(tid>>3)*8 + (tid&7)] = (_Float16)xnext;
        }
        if (t >= 0){
            // --- z2(t): A kk<4 = AH1B[pe], kk>=4 = AH2[pe] ---
            floatx4 a2[2];
            #pragma unroll
            for (int i = 0; i < 2; ++i) a2[i] = (floatx4){z2b[i],z2b[i],z2b[i],z2b[i]};
            #pragma unroll
            for (int kk = 0; kk < 6; ++kk){
                half8 a = (kk < 4) ? *(const half8*)&AH1B[pe][kk][l*8]
                                   : *(const half8*)&AH2[pe][kk-4][l*8];
                #pragma unroll
                for (int i = 0; i < 2; ++i)
                    a2[i] = MFMAH(a, wz2[i][kk], a2[i]);
            }
            // --- cell2(t) fully in-register (gate-permuted columns) ---
            float a2p[2][2];
            #pragma unroll
            for (int i = 0; i < 2; ++i){
                float t2 = __shfl_xor(a2[i][2], 32);
                float t3 = __shfl_xor(a2[i][3], 32);
                a2p[i][0] = hi ? t2 : a2[i][0];
                a2p[i][1] = hi ? t3 : a2[i][1];
            }
            float e00 = __shfl_xor(a2p[0][0], 8);
            float e01 = __shfl_xor(a2p[0][1], 8);
            float e10 = __shfl_xor(a2p[1][0], 8);
            float e11 = __shfl_xor(a2p[1][1], 8);
            float zi = h8 ? e01       : a2p[0][0];
            float zf = h8 ? a2p[0][1] : e00;
            float zg = h8 ? e11       : a2p[1][0];
            float zo = h8 ? a2p[1][1] : e10;
            float ig = sigmoid_(zi);
            float fg = sigmoid_(zf);
            float gg = selu_(zg);
            float og = sigmoid_(zo);
            float c = fg*c2r + ig*gg; c2r = c;
            h2last = og*selu_(c);
            AH2[pe^1][w>>2][s2w] = (_Float16)h2last;
        }
        __syncthreads();
    }

    // ===================== bottleneck =====================
    // encb = BN2(h2_final) from register -> AH3B[1] scratch planes
    AH3B[1][w>>2][s2w] = (_Float16)(h2last*s2v + t2v);
    __syncthreads();
    // xz3 = b3 + encb@Wk3  (one-time)
    floatx4 xz3r[4];
    if (w < 4){
        #pragma unroll
        for (int i = 0; i < 4; ++i) xz3r[i] = (floatx4){b3v[i],b3v[i],b3v[i],b3v[i]};
        #pragma unroll
        for (int kk = 0; kk < 2; ++kk){
            half8 a = *(const half8*)&AH3B[1][kk][l*8];
            #pragma unroll
            for (int i = 0; i < 4; ++i){
                half8 b = *(const half8*)(WS + (size_t)(FS_X3 + ((w&3)+4*i)*2 + kk)*512 + l*8);
                xz3r[i] = MFMAH(a, b, xz3r[i]);
            }
        }
    }

    // ---- decoder weights pinned in AGPRs (encoder AGPRs now dead) ----
    half8 wz4[4][6], wrole[8];
    #pragma unroll
    for (int i = 0; i < 4; ++i)
        #pragma unroll
        for (int kk = 0; kk < 6; ++kk){
            wz4[i][kk] = *(const half8*)(WS + (size_t)(FS_Z4 + (w+8*i)*6 + kk)*512 + l*8);
            PINA(wz4[i][kk]);
        }
    if (w < 4){
        #pragma unroll
        for (int i = 0; i < 4; ++i)
            #pragma unroll
            for (int kk = 0; kk < 2; ++kk){
                wrole[i*2+kk] = *(const half8*)(WS + (size_t)(FS_Z3 + ((w&3)+4*i)*2 + kk)*512 + l*8);
                PINA(wrole[i*2+kk]);
            }
    } else if (w == 4){
        #pragma unroll
        for (int kk = 0; kk < 4; ++kk){
            wrole[kk] = *(const half8*)(WS + (size_t)(FS_DN + kk)*512 + l*8);
            PINA(wrole[kk]);
        }
    }
    __syncthreads();

    // ===================== decoder: ONE barrier per step =====================
    // region_t: z3(t+1)+cell3(t+1) (w<4) | z4(t)+cell4(t) (all) | dense(t-1) (w4)
    for (int t = -1; t < TT; ++t){
        const int pd = t & 1;
        if (w < 4 && t + 1 < TT){
            floatx4 a3[4];
            #pragma unroll
            for (int i = 0; i < 4; ++i) a3[i] = xz3r[i];
            #pragma unroll
            for (int kk = 0; kk < 2; ++kk){
                half8 a = *(const half8*)&AH3[pd^1][kk][l*8];
                #pragma unroll
                for (int i = 0; i < 4; ++i)
                    a3[i] = MFMAH(a, wrole[i*2+kk], a3[i]);
            }
            float ga[2][4];
            #pragma unroll
            for (int i = 0; i < 4; ++i){
                float t2 = __shfl_xor(a3[i][2], 32);
                float t3 = __shfl_xor(a3[i][3], 32);
                ga[0][i] = hi ? t2 : a3[i][0];
                ga[1][i] = hi ? t3 : a3[i][1];
            }
            #pragma unroll
            for (int r = 0; r < 2; ++r){
                float ig = sigmoid_(ga[r][0]);
                float fg = sigmoid_(ga[r][1]);
                float gg = selu_(ga[r][2]);
                float og = sigmoid_(ga[r][3]);
                float c = fg*c3r[r] + ig*gg; c3r[r] = c;
                float h = og*selu_(c);
                const int s = sbase3 + (rowA+r)*8;
                AH3[pd][kk3][s]     = (_Float16)h;
                AH3B[pd^1][kk3][s]  = (_Float16)(h*s3v + t3v);
            }
        } else if (w == 4 && t > 0){
            // dense(t-1): A = AH4B[pd^1], B = Wd
            floatx4 ad = (floatx4){bdv,bdv,bdv,bdv};
            #pragma unroll
            for (int kk = 0; kk < 4; ++kk){
                half8 a = *(const half8*)&AH4B[pd^1][kk][l*8];
                ad = MFMAH(a, wrole[kk], ad);
            }
            if (q < 2 && l15 < 8){
                #pragma unroll
                for (int r = 0; r < 4; ++r)
                    out[(size_t)(b0 + q*4 + r)*(TT*NF) + (size_t)(t-1)*NF + l15] = ad[r];
            }
        }
        if (t >= 0){
            // --- z4(t): A kk<2 = AH3B[pd], kk>=2 = AH4[pd] ---
            floatx4 a4[4];
            #pragma unroll
            for (int i = 0; i < 4; ++i) a4[i] = (floatx4){z4b[i],z4b[i],z4b[i],z4b[i]};
            #pragma unroll
            for (int kk = 0; kk < 6; ++kk){
                half8 a = (kk < 2) ? *(const half8*)&AH3B[pd][kk][l*8]
                                   : *(const half8*)&AH4[pd][kk-2][l*8];
                #pragma unroll
                for (int i = 0; i < 4; ++i)
                    a4[i] = MFMAH(a, wz4[i][kk], a4[i]);
            }
            float ga[2][4];
            #pragma unroll
            for (int i = 0; i < 4; ++i){
                float t2 = __shfl_xor(a4[i][2], 32);
                float t3 = __shfl_xor(a4[i][3], 32);
                ga[0][i] = hi ? t2 : a4[i][0];
                ga[1][i] = hi ? t3 : a4[i][1];
            }
            #pragma unroll
            for (int r = 0; r < 2; ++r){
                float ig = sigmoid_(ga[r][0]);
                float fg = sigmoid_(ga[r][1]);
                float gg = selu_(ga[r][2]);
                float og = sigmoid_(ga[r][3]);
                float c = fg*c4r[r] + ig*gg; c4r[r] = c;
                float h = og*selu_(c);
                const int s = sbase1 + (rowA+r)*8;
                AH4[pd^1][kk1][s] = (_Float16)h;
                AH4B[pd][kk1][s]  = (_Float16)(h*s4v + t4v);
            }
        }
        __syncthreads();
    }

    // epilogue: dense for t = TT-1 (wave4); cell4(TT-1) wrote AH4B[(TT-1)&1]
    if (w == 4){
        floatx4 ad = (floatx4){bdv,bdv,bdv,bdv};
        #pragma unroll
        for (int kk = 0; kk < 4; ++kk){
            half8 a = *(const half8*)&AH4B[(TT-1)&1][kk][l*8];
            ad = MFMAH(a, wrole[kk], ad);
        }
        if (q < 2 && l15 < 8){
            #pragma unroll
            for (int r = 0; r < 4; ++r)
                out[(size_t)(b0 + q*4 + r)*(TT*NF) + (size_t)(TT-1)*NF + l15] = ad[r];
        }
    }
}

extern "C" void kernel_launch(void* const* d_in, const int* in_sizes, int n_in,
                              void* d_out, int out_size, void* d_ws, size_t ws_size,
                              hipStream_t stream) {
    const float* x   = (const float*)d_in[0];
    const float* Wk1 = (const float*)d_in[1];  const float* Wr1 = (const float*)d_in[2];
    const float* b1  = (const float*)d_in[3];
    const float* g1  = (const float*)d_in[4];  const float* be1 = (const float*)d_in[5];
    const float* m1  = (const float*)d_in[6];  const float* v1  = (const float*)d_in[7];
    const float* Wk2 = (const float*)d_in[8];  const float* Wr2 = (const float*)d_in[9];
    const float* b2  = (const float*)d_in[10];
    const float* g2  = (const float*)d_in[11]; const float* be2 = (const float*)d_in[12];
    const float* m2  = (const float*)d_in[13]; const float* v2  = (const float*)d_in[14];
    const float* Wk3 = (const float*)d_in[15]; const float* Wr3 = (const float*)d_in[16];
    const float* b3  = (const float*)d_in[17];
    const float* g3  = (const float*)d_in[18]; const float* be3 = (const float*)d_in[19];
    const float* m3  = (const float*)d_in[20]; const float* v3  = (const float*)d_in[21];
    const float* Wk4 = (const float*)d_in[22]; const float* Wr4 = (const float*)d_in[23];
    const float* b4  = (const float*)d_in[24];
    const float* g4  = (const float*)d_in[25]; const float* be4 = (const float*)d_in[26];
    const float* m4  = (const float*)d_in[27]; const float* v4  = (const float*)d_in[28];
    const float* Wd  = (const float*)d_in[29]; const float* bd  = (const float*)d_in[30];

    unsigned short* ws = (unsigned short*)d_ws;

    pack_kernel<<<dim3(N_FRAGS), dim3(64), 0, stream>>>(Wk1, Wr1, Wk2, Wr2, Wk3, Wr3,
                                                        Wk4, Wr4, Wd, ws);
    lstm_ae_mfma<<<dim3(NBLK), dim3(NTH), 0, stream>>>(
        x, b1, b2, b3, b4, bd,
        g1, be1, m1, v1, g2, be2, m2, v2,
        g3, be3, m3, v3, g4, be4, m4, v4,
        (const unsigned short*)ws, (float*)d_out);
}

// Round 4
// 438.058 us; speedup vs baseline: 1.6722x; 1.0831x over previous
//
#include <hip/hip_runtime.h>
#include <math.h>

// LSTM autoencoder, MFMA, fp16 single-product numerics.
// R13 = R12 with "spread-row" A-row mapping: batch row br -> A-row
// (br&1)+4*(br>>1), so valid C rows are {4q,4q+1} in EVERY lane quarter q.
// Each lane natively owns its 2 cells in acc regs 0-1: the post-MFMA
// shfl_xor(32)+cndmask rebalance (8 ds_bpermute + 8 sel per z-group, on the
// critical path) is deleted from cell1/3/4; cell2 drops to one exchange stage
// (2 shfl_xor(8) + 8 sel). Bit-identical math per batch row.
// Carried from R12:
//  - ONE barrier per recurrent step: retimed regions with dbuf BN planes.
//  - gate-permuted z2 -> in-register cell2 (no ZSC round trip).
//  - rcpf sigmoid; NO BN fold; weights pinned in AGPRs (enc/dec disjoint).
//  - 128 VGPR + 128 AGPR = 2 waves/SIMD cliff; register-neutral changes only.
// 256 blocks x 512 threads, BT=8 rows/block.

typedef _Float16 half8 __attribute__((ext_vector_type(8)));
typedef __attribute__((ext_vector_type(4))) float floatx4;

#define TT 128
#define NF 8
#define BT 8
#define NBLK 256
#define NTH 512

// packed-fragment start indices (in 512-ushort frag units, single fp16 plane)
#define FS_Z1 0     // K'=160 (Wr1 128 | Wk1 8 | pad), N=512 : 32 tiles x 5 ks
#define FS_Z2 160   // K'=192 (Wk2 128 | Wr2 64),     N=256 : 16 x 6  (cols gate-permuted)
#define FS_X3 256   // K =64  (Wk3),                  N=256 : 16 x 2
#define FS_Z3 288   // K =64  (Wr3),                  N=256 : 16 x 2
#define FS_Z4 320   // K'=192 (Wk4 64 | Wr4 128),     N=512 : 32 x 6
#define FS_DN 512   // K =128 (Wd), N=16 (cols 8-15 zero) : 1 x 4
#define N_FRAGS 516

#define MFMAH(a,b,c) __builtin_amdgcn_mfma_f32_16x16x32_f16((a),(b),(c),0,0,0)
#define PINA(v) asm volatile("" : "+a"(v))

__device__ __forceinline__ float sigmoid_(float x){
    return __builtin_amdgcn_rcpf(1.0f + __expf(-x));
}
__device__ __forceinline__ float selu_(float x){
    const float alpha = 1.6732632423543772f, scale = 1.0507009873554805f;
    return x > 0.0f ? scale*x : scale*alpha*(__expf(x)-1.0f);
}

// ---------------- pack kernel: RAW weights -> B-fragment order, fp16 --------
__global__ void pack_kernel(const float* __restrict__ Wk1, const float* __restrict__ Wr1,
                            const float* __restrict__ Wk2, const float* __restrict__ Wr2,
                            const float* __restrict__ Wk3, const float* __restrict__ Wr3,
                            const float* __restrict__ Wk4, const float* __restrict__ Wr4,
                            const float* __restrict__ Wd, unsigned short* __restrict__ ws)
{
    const int g = blockIdx.x;
    const int l = threadIdx.x;
    int blob, fs, KS;
    if      (g < FS_Z2){ blob = 0; fs = FS_Z1; KS = 5; }
    else if (g < FS_X3){ blob = 1; fs = FS_Z2; KS = 6; }
    else if (g < FS_Z3){ blob = 2; fs = FS_X3; KS = 2; }
    else if (g < FS_Z4){ blob = 3; fs = FS_Z3; KS = 2; }
    else if (g < FS_DN){ blob = 4; fs = FS_Z4; KS = 6; }
    else               { blob = 5; fs = FS_DN; KS = 4; }
    const int fl = g - fs;
    const int tile = fl / KS, kk = fl % KS;
    const int c   = l & 15;
    const int col = tile * 16 + c;
    const int k0  = kk * 32 + (l >> 4) * 8;
    // z2 gate-permuted column: wave w=tile>>1 owns units 8w..8w+7, all 4 gates
    const int oc2 = (2*(tile&1) + (c>>3))*64 + 8*(tile>>1) + (c&7);

    half8 v8;
    #pragma unroll
    for (int j = 0; j < 8; ++j){
        const int k = k0 + j;
        float v = 0.0f;
        switch (blob){
            case 0: v = (k < 128) ? Wr1[k*512 + col] : (k < 136 ? Wk1[(k-128)*512 + col] : 0.0f); break;
            case 1: v = (k < 128) ? Wk2[k*256 + oc2] : Wr2[(k-128)*256 + oc2]; break;
            case 2: v = Wk3[k*256 + col]; break;
            case 3: v = Wr3[k*256 + col]; break;
            case 4: v = (k < 64) ? Wk4[k*512 + col] : Wr4[(k-64)*512 + col]; break;
            case 5: v = (col < 8) ? Wd[k*8 + col] : 0.0f; break;
        }
        v8[j] = (_Float16)v;    // RNE
    }
    *(half8*)(ws + (size_t)g*512 + l*8) = v8;
}

// ---------------- main kernel ------------------------------------------------
__global__ __launch_bounds__(NTH, 1) void lstm_ae_mfma(
    const float* __restrict__ x,
    const float* __restrict__ b1, const float* __restrict__ b2,
    const float* __restrict__ b3, const float* __restrict__ b4,
    const float* __restrict__ bd,
    const float* __restrict__ g1, const float* __restrict__ be1, const float* __restrict__ m1, const float* __restrict__ v1,
    const float* __restrict__ g2, const float* __restrict__ be2, const float* __restrict__ m2, const float* __restrict__ v2,
    const float* __restrict__ g3, const float* __restrict__ be3, const float* __restrict__ m3, const float* __restrict__ v3,
    const float* __restrict__ g4, const float* __restrict__ be4, const float* __restrict__ m4, const float* __restrict__ v4,
    const unsigned short* __restrict__ WS,
    float* __restrict__ out)
{
    // A-fragment planes, fp16: [buf][kk][lane*8+j]
    // spread-row map: batch row br lives at A-row (br&1)+4*(br>>1);
    // A-rows {2,3,6,7,10,11,14,15} stay exact zero forever.
    __shared__ __align__(16) _Float16 AZ1[2][5][512];   // h1 (kk 0-3) + x (kk 4)
    __shared__ __align__(16) _Float16 AH1B[2][4][512];  // BN1(h1), double-buffered
    __shared__ __align__(16) _Float16 AH2[2][2][512];
    __shared__ __align__(16) _Float16 AH3[2][2][512];
    __shared__ __align__(16) _Float16 AH3B[2][2][512];  // BN3(h3) dbuf; [1] = enc scratch
    __shared__ __align__(16) _Float16 AH4[2][4][512];
    __shared__ __align__(16) _Float16 AH4B[2][4][512];  // BN4(h4), double-buffered

    const int tid = threadIdx.x;
    const int w = tid >> 6, l = tid & 63;
    const int l15 = l & 15, q = l >> 4;
    const int h8 = (l15 >> 3) & 1;      // gate-exchange side for cell2
    const int b0 = blockIdx.x * BT;
    // lane's 2 A-rows are 4q+0, 4q+1 == batch rows 2q+0, 2q+1 (acc regs 0,1)
    const int arow0 = 4*q;

    // ---- per-lane constants ----
    const int u1 = 16*w + l15;                   // z1/z4 cell column (0..127)
    const int kk1 = u1 >> 5;
    const int sbase1 = ((u1>>3)&3)*128 + (u1&7);
    const float s1v = g1[u1]*rsqrtf(v1[u1]+1e-3f), t1v = be1[u1]-m1[u1]*s1v;
    const float s4v = g4[u1]*rsqrtf(v4[u1]+1e-3f), t4v = be4[u1]-m4[u1]*s4v;

    // encoder cell2 mapping (gate-permuted z2): one cell/lane, row 2q+h8
    const int u2n = 8*w + (l15 & 7);             // unit 0..63
    const int s2w = (w&3)*128 + (arow0 + h8)*8 + (l15&7); // A-row 4q+h8
    const float s2v = g2[u2n]*rsqrtf(v2[u2n]+1e-3f), t2v = be2[u2n]-m2[u2n]*s2v;

    // decoder cell3 mapping (waves 0-3 own all gates of column u3)
    const int u3 = 16*(w&3) + l15;               // 0..63
    const int kk3 = u3 >> 5;
    const int sbase3 = ((u3>>3)&3)*128 + (u3&7);
    const float s3v = g3[u3]*rsqrtf(v3[u3]+1e-3f);
    const float t3v = be3[u3]-m3[u3]*s3v;

    float z1b[4], z4b[4], z2b[2];
    #pragma unroll
    for (int i = 0; i < 4; ++i){
        z1b[i] = b1[(w + 8*i)*16 + l15];
        z4b[i] = b4[(w + 8*i)*16 + l15];
    }
    #pragma unroll
    for (int i = 0; i < 2; ++i)
        z2b[i] = b2[(2*i + h8)*64 + u2n];        // permuted-column bias
    float b3v[4];
    #pragma unroll
    for (int i = 0; i < 4; ++i)
        b3v[i] = (w < 4) ? b3[((w&3) + 4*i)*16 + l15] : 0.0f;
    const float bdv = (w == 4 && l15 < 8) ? bd[l15] : 0.0f;

    // ---- encoder weights pinned in AGPRs ----
    half8 wz1[4][5], wz2[2][6];
    #pragma unroll
    for (int i = 0; i < 4; ++i)
        #pragma unroll
        for (int kk = 0; kk < 5; ++kk){
            wz1[i][kk] = *(const half8*)(WS + (size_t)(FS_Z1 + (w+8*i)*5 + kk)*512 + l*8);
            PINA(wz1[i][kk]);
        }
    #pragma unroll
    for (int i = 0; i < 2; ++i)
        #pragma unroll
        for (int kk = 0; kk < 6; ++kk){
            wz2[i][kk] = *(const half8*)(WS + (size_t)(FS_Z2 + (2*w+i)*6 + kk)*512 + l*8);
            PINA(wz2[i][kk]);
        }

    // ---- prologue: zero all planes, stage x(0) at spread rows ----
    for (int i = tid; i < 2560; i += NTH) ((int*)AZ1)[i] = 0;
    for (int i = tid; i < 2048; i += NTH){
        ((int*)AH1B)[i] = 0; ((int*)AH4)[i] = 0; ((int*)AH4B)[i] = 0;
    }
    for (int i = tid; i < 1024; i += NTH){
        ((int*)AH2)[i] = 0; ((int*)AH3)[i] = 0; ((int*)AH3B)[i] = 0;
    }
    if (tid < 64){
        const int br = tid >> 3, ar = (br & 1) + 4*(br >> 1);
        AZ1[0][4][ar*8 + (tid&7)] = (_Float16)x[(size_t)(b0+br)*(TT*NF) + (tid&7)];
    }
    float c1r[2] = {0,0}, c4r[2] = {0,0}, c3r[2] = {0,0};
    float c2r = 0.0f, h2last = 0.0f;
    __syncthreads();

    // ===================== encoder: ONE barrier per step =====================
    // region_t: z1(t+1)+cell1(t+1) | z2(t)+cell2(t)   (t = -1 .. TT-1)
    for (int t = -1; t < TT; ++t){
        const int pe = t & 1;      // (-1)&1 == 1
        if (t + 1 < TT){
            float xnext = 0.0f;
            if (tid < 64 && t + 2 < TT)
                xnext = x[(size_t)(b0+(tid>>3))*(TT*NF) + (size_t)(t+2)*NF + (tid&7)];

            // --- z1(t+1): A from AZ1[pe^1], B from AGPR ---
            floatx4 acc[4];
            #pragma unroll
            for (int i = 0; i < 4; ++i) acc[i] = (floatx4){z1b[i],z1b[i],z1b[i],z1b[i]};
            #pragma unroll
            for (int kk = 0; kk < 5; ++kk){
                half8 a = *(const half8*)&AZ1[pe^1][kk][l*8];
                #pragma unroll
                for (int i = 0; i < 4; ++i)
                    acc[i] = MFMAH(a, wz1[i][kk], acc[i]);
            }
            // --- cell1(t+1): regs 0,1 are this lane's rows -- NO shuffle ---
            #pragma unroll
            for (int r = 0; r < 2; ++r){
                float ig = sigmoid_(acc[0][r]);
                float fg = sigmoid_(acc[1][r]);
                float gg = selu_(acc[2][r]);
                float og = sigmoid_(acc[3][r]);
                float c = fg*c1r[r] + ig*gg; c1r[r] = c;
                float h = og*selu_(c);
                const int s = sbase1 + (arow0 + r)*8;
                AZ1[pe][kk1][s]    = (_Float16)h;
                AH1B[pe^1][kk1][s] = (_Float16)(h*s1v + t1v);
            }
            if (tid < 64 && t + 2 < TT){
                const int br = tid >> 3, ar = (br & 1) + 4*(br >> 1);
                AZ1[pe][4][ar*8 + (tid&7)] = (_Float16)xnext;
            }
        }
        if (t >= 0){
            // --- z2(t): A kk<4 = AH1B[pe], kk>=4 = AH2[pe] ---
            floatx4 a2[2];
            #pragma unroll
            for (int i = 0; i < 2; ++i) a2[i] = (floatx4){z2b[i],z2b[i],z2b[i],z2b[i]};
            #pragma unroll
            for (int kk = 0; kk < 6; ++kk){
                half8 a = (kk < 4) ? *(const half8*)&AH1B[pe][kk][l*8]
                                   : *(const half8*)&AH2[pe][kk-4][l*8];
                #pragma unroll
                for (int i = 0; i < 2; ++i)
                    a2[i] = MFMAH(a, wz2[i][kk], a2[i]);
            }
            // --- cell2(t) in-register: one xor-8 exchange stage ---
            // own gates at row 2q+h8 in reg h8; partner (l15^8) supplies the
            // other 2 gates for the SAME row via give/exchange.
            float keep0 = h8 ? a2[0][1] : a2[0][0];
            float keep1 = h8 ? a2[1][1] : a2[1][0];
            float give0 = h8 ? a2[0][0] : a2[0][1];
            float give1 = h8 ? a2[1][0] : a2[1][1];
            float e0 = __shfl_xor(give0, 8);
            float e1 = __shfl_xor(give1, 8);
            float zi = h8 ? e0    : keep0;
            float zf = h8 ? keep0 : e0;
            float zg = h8 ? e1    : keep1;
            float zo = h8 ? keep1 : e1;
            float ig = sigmoid_(zi);
            float fg = sigmoid_(zf);
            float gg = selu_(zg);
            float og = sigmoid_(zo);
            float c = fg*c2r + ig*gg; c2r = c;
            h2last = og*selu_(c);
            AH2[pe^1][w>>2][s2w] = (_Float16)h2last;
        }
        __syncthreads();
    }

    // ===================== bottleneck =====================
    // encb = BN2(h2_final) from register -> AH3B[1] scratch planes
    AH3B[1][w>>2][s2w] = (_Float16)(h2last*s2v + t2v);
    __syncthreads();
    // xz3 = b3 + encb@Wk3  (one-time)
    floatx4 xz3r[4];
    if (w < 4){
        #pragma unroll
        for (int i = 0; i < 4; ++i) xz3r[i] = (floatx4){b3v[i],b3v[i],b3v[i],b3v[i]};
        #pragma unroll
        for (int kk = 0; kk < 2; ++kk){
            half8 a = *(const half8*)&AH3B[1][kk][l*8];
            #pragma unroll
            for (int i = 0; i < 4; ++i){
                half8 b = *(const half8*)(WS + (size_t)(FS_X3 + ((w&3)+4*i)*2 + kk)*512 + l*8);
                xz3r[i] = MFMAH(a, b, xz3r[i]);
            }
        }
    }

    // ---- decoder weights pinned in AGPRs (encoder AGPRs now dead) ----
    half8 wz4[4][6], wrole[8];
    #pragma unroll
    for (int i = 0; i < 4; ++i)
        #pragma unroll
        for (int kk = 0; kk < 6; ++kk){
            wz4[i][kk] = *(const half8*)(WS + (size_t)(FS_Z4 + (w+8*i)*6 + kk)*512 + l*8);
            PINA(wz4[i][kk]);
        }
    if (w < 4){
        #pragma unroll
        for (int i = 0; i < 4; ++i)
            #pragma unroll
            for (int kk = 0; kk < 2; ++kk){
                wrole[i*2+kk] = *(const half8*)(WS + (size_t)(FS_Z3 + ((w&3)+4*i)*2 + kk)*512 + l*8);
                PINA(wrole[i*2+kk]);
            }
    } else if (w == 4){
        #pragma unroll
        for (int kk = 0; kk < 4; ++kk){
            wrole[kk] = *(const half8*)(WS + (size_t)(FS_DN + kk)*512 + l*8);
            PINA(wrole[kk]);
        }
    }
    __syncthreads();

    // ===================== decoder: ONE barrier per step =====================
    // region_t: z3(t+1)+cell3(t+1) (w<4) | z4(t)+cell4(t) (all) | dense(t-1) (w4)
    for (int t = -1; t < TT; ++t){
        const int pd = t & 1;
        if (w < 4 && t + 1 < TT){
            floatx4 a3[4];
            #pragma unroll
            for (int i = 0; i < 4; ++i) a3[i] = xz3r[i];
            #pragma unroll
            for (int kk = 0; kk < 2; ++kk){
                half8 a = *(const half8*)&AH3[pd^1][kk][l*8];
                #pragma unroll
                for (int i = 0; i < 4; ++i)
                    a3[i] = MFMAH(a, wrole[i*2+kk], a3[i]);
            }
            #pragma unroll
            for (int r = 0; r < 2; ++r){
                float ig = sigmoid_(a3[0][r]);
                float fg = sigmoid_(a3[1][r]);
                float gg = selu_(a3[2][r]);
                float og = sigmoid_(a3[3][r]);
                float c = fg*c3r[r] + ig*gg; c3r[r] = c;
                float h = og*selu_(c);
                const int s = sbase3 + (arow0 + r)*8;
                AH3[pd][kk3][s]     = (_Float16)h;
                AH3B[pd^1][kk3][s]  = (_Float16)(h*s3v + t3v);
            }
        } else if (w == 4 && t > 0){
            // dense(t-1): A = AH4B[pd^1], B = Wd
            floatx4 ad = (floatx4){bdv,bdv,bdv,bdv};
            #pragma unroll
            for (int kk = 0; kk < 4; ++kk){
                half8 a = *(const half8*)&AH4B[pd^1][kk][l*8];
                ad = MFMAH(a, wrole[kk], ad);
            }
            if (l15 < 8){
                #pragma unroll
                for (int r = 0; r < 2; ++r)
                    out[(size_t)(b0 + 2*q + r)*(TT*NF) + (size_t)(t-1)*NF + l15] = ad[r];
            }
        }
        if (t >= 0){
            // --- z4(t): A kk<2 = AH3B[pd], kk>=2 = AH4[pd] ---
            floatx4 a4[4];
            #pragma unroll
            for (int i = 0; i < 4; ++i) a4[i] = (floatx4){z4b[i],z4b[i],z4b[i],z4b[i]};
            #pragma unroll
            for (int kk = 0; kk < 6; ++kk){
                half8 a = (kk < 2) ? *(const half8*)&AH3B[pd][kk][l*8]
                                   : *(const half8*)&AH4[pd][kk-2][l*8];
                #pragma unroll
                for (int i = 0; i < 4; ++i)
                    a4[i] = MFMAH(a, wz4[i][kk], a4[i]);
            }
            #pragma unroll
            for (int r = 0; r < 2; ++r){
                float ig = sigmoid_(a4[0][r]);
                float fg = sigmoid_(a4[1][r]);
                float gg = selu_(a4[2][r]);
                float og = sigmoid_(a4[3][r]);
                float c = fg*c4r[r] + ig*gg; c4r[r] = c;
                float h = og*selu_(c);
                const int s = sbase1 + (arow0 + r)*8;
                AH4[pd^1][kk1][s] = (_Float16)h;
                AH4B[pd][kk1][s]  = (_Float16)(h*s4v + t4v);
            }
        }
        __syncthreads();
    }

    // epilogue: dense for t = TT-1 (wave4); cell4(TT-1) wrote AH4B[(TT-1)&1]
    if (w == 4){
        floatx4 ad = (floatx4){bdv,bdv,bdv,bdv};
        #pragma unroll
        for (int kk = 0; kk < 4; ++kk){
            half8 a = *(const half8*)&AH4B[(TT-1)&1][kk][l*8];
            ad = MFMAH(a, wrole[kk], ad);
        }
        if (l15 < 8){
            #pragma unroll
            for (int r = 0; r < 2; ++r)
                out[(size_t)(b0 + 2*q + r)*(TT*NF) + (size_t)(TT-1)*NF + l15] = ad[r];
        }
    }
}

extern "C" void kernel_launch(void* const* d_in, const int* in_sizes, int n_in,
                              void* d_out, int out_size, void* d_ws, size_t ws_size,
                              hipStream_t stream) {
    const float* x   = (const float*)d_in[0];
    const float* Wk1 = (const float*)d_in[1];  const float* Wr1 = (const float*)d_in[2];
    const float* b1  = (const float*)d_in[3];
    const float* g1  = (const float*)d_in[4];  const float* be1 = (const float*)d_in[5];
    const float* m1  = (const float*)d_in[6];  const float* v1  = (const float*)d_in[7];
    const float* Wk2 = (const float*)d_in[8];  const float* Wr2 = (const float*)d_in[9];
    const float* b2  = (const float*)d_in[10];
    const float* g2  = (const float*)d_in[11]; const float* be2 = (const float*)d_in[12];
    const float* m2  = (const float*)d_in[13]; const float* v2  = (const float*)d_in[14];
    const float* Wk3 = (const float*)d_in[15]; const float* Wr3 = (const float*)d_in[16];
    const float* b3  = (const float*)d_in[17];
    const float* g3  = (const float*)d_in[18]; const float* be3 = (const float*)d_in[19];
    const float* m3  = (const float*)d_in[20]; const float* v3  = (const float*)d_in[21];
    const float* Wk4 = (const float*)d_in[22]; const float* Wr4 = (const float*)d_in[23];
    const float* b4  = (const float*)d_in[24];
    const float* g4  = (const float*)d_in[25]; const float* be4 = (const float*)d_in[26];
    const float* m4  = (const float*)d_in[27]; const float* v4  = (const float*)d_in[28];
    const float* Wd  = (const float*)d_in[29]; const float* bd  = (const float*)d_in[30];

    unsigned short* ws = (unsigned short*)d_ws;

    pack_kernel<<<dim3(N_FRAGS), dim3(64), 0, stream>>>(Wk1, Wr1, Wk2, Wr2, Wk3, Wr3,
                                                        Wk4, Wr4, Wd, ws);
    lstm_ae_mfma<<<dim3(NBLK), dim3(NTH), 0, stream>>>(
        x, b1, b2, b3, b4, bd,
        g1, be1, m1, v1, g2, be2, m2, v2,
        g3, be3, m3, v3, g4, be4, m4, v4,
        (const unsigned short*)ws, (float*)d_out);
}